// Round 3
// baseline (494.903 us; speedup 1.0000x reference)
//
#include <hip/hip_runtime.h>
#include <hip/hip_bf16.h>

#define NT 4096      // H*W
#define CF 256       // feature channels
// CQK = 64

typedef __attribute__((ext_vector_type(8))) short bf16x8;
typedef __attribute__((ext_vector_type(4))) float f32x4;
typedef __attribute__((ext_vector_type(4))) short s16x4;

__device__ __forceinline__ short f2bf(float f) {
  union { float f; unsigned u; } v; v.f = f;
  unsigned r = v.u + 0x7FFFu + ((v.u >> 16) & 1u);   // RTNE
  return (short)(r >> 16);
}

// ---------------------------------------------------------------------------
// Projection: Y[i,o] = (sum_c X[c,i] * W[o,c] + bias[o]) * scale, bf16 output.
// TRANS=false -> Y (B,NT,O) row-major;  TRANS=true -> Y (B,O,NT).
// ---------------------------------------------------------------------------
template<int O, bool TRANS>
__global__ __launch_bounds__(256, 2)
void proj_kernel(const float* __restrict__ X, const float* __restrict__ W,
                 const float* __restrict__ Bv, short* __restrict__ Y, float scale)
{
  __shared__ alignas(16) short Xlds[64 * 256];   // [i][c] bf16, XOR-swizzled
  const int tid = threadIdx.x;
  const int wv = tid >> 6, l = tid & 63;
  const int l15 = l & 15, l4 = l >> 4;
  const int i0 = blockIdx.x * 64;
  const int b  = blockIdx.y;
  const float* Xb = X + (size_t)b * CF * NT;

#pragma unroll
  for (int it = 0; it < 16; ++it) {
    int c0 = it * 16 + wv * 4;
    float x0 = Xb[(size_t)(c0 + 0) * NT + i0 + l];
    float x1 = Xb[(size_t)(c0 + 1) * NT + i0 + l];
    float x2 = Xb[(size_t)(c0 + 2) * NT + i0 + l];
    float x3 = Xb[(size_t)(c0 + 3) * NT + i0 + l];
    s16x4 pk; pk[0] = f2bf(x0); pk[1] = f2bf(x1); pk[2] = f2bf(x2); pk[3] = f2bf(x3);
    int phys = (l * 512 + c0 * 2) ^ ((l & 31) << 4);
    *(s16x4*)((char*)Xlds + phys) = pk;
  }
  __syncthreads();

  constexpr int NO = O / 64;
  f32x4 acc[4][NO] = {};

#pragma unroll
  for (int kk = 0; kk < 8; ++kk) {
    bf16x8 a[4];
#pragma unroll
    for (int mi = 0; mi < 4; ++mi) {
      int i = 16 * mi + l15;
      int phys = (i * 512 + kk * 64 + l4 * 16) ^ ((i & 31) << 4);
      a[mi] = *(const bf16x8*)((const char*)Xlds + phys);
    }
#pragma unroll
    for (int no = 0; no < NO; ++no) {
      int o = wv * (O / 4) + 16 * no + l15;
      const float* wp = W + (size_t)o * CF + kk * 32 + l4 * 8;
      bf16x8 wf;
#pragma unroll
      for (int t = 0; t < 8; ++t) wf[t] = f2bf(wp[t]);
#pragma unroll
      for (int mi = 0; mi < 4; ++mi)
        acc[mi][no] = __builtin_amdgcn_mfma_f32_16x16x32_bf16(a[mi], wf, acc[mi][no], 0, 0, 0);
    }
  }

#pragma unroll
  for (int no = 0; no < NO; ++no) {
    int o = wv * (O / 4) + 16 * no + l15;
    float bv = Bv[o];
#pragma unroll
    for (int mi = 0; mi < 4; ++mi) {
      if (TRANS) {
        s16x4 pk;
#pragma unroll
        for (int r = 0; r < 4; ++r) pk[r] = f2bf((acc[mi][no][r] + bv) * scale);
        *(s16x4*)&Y[((size_t)b * O + o) * NT + i0 + 16 * mi + l4 * 4] = pk;
      } else {
#pragma unroll
        for (int r = 0; r < 4; ++r) {
          int i = i0 + 16 * mi + l4 * 4 + r;
          Y[((size_t)b * NT + i) * O + o] = f2bf((acc[mi][no][r] + bv) * scale);
        }
      }
    }
  }
}

// ---------------------------------------------------------------------------
// Flash attention + residual — barrier-free main loop, 64-col wave strips.
// Q (B,NT,64) bf16 pre-scaled by (1/16)*log2(e)  (scores in log2 domain),
// K (B,NT,64) bf16, Vt (B,256,NT) bf16.
// Wave owns 16 q-rows x 64 out-cols, fully independent (no barriers).
// Swapped QK^T (S^T = K_perm @ Q^T) with key permutation
//   kappa(nj,a) = 32*(nj>>1) + 4*(nj&1) + 8*(a>>2) + (a&3)
// so each lane's 16 scores are exactly the PV A-fragment k-slots:
// P stays in registers (cvt_pk), no LDS in the loop.
// ---------------------------------------------------------------------------
__global__ __launch_bounds__(256, 3)
void flash_kernel(const short* __restrict__ Q, const short* __restrict__ K,
                  const short* __restrict__ Vt, const float* __restrict__ src,
                  const float* __restrict__ gamma_p, float* __restrict__ out)
{
  __shared__ float Obuf[4][16][68];   // epilogue transpose only (per-wave)

  const int tid = threadIdx.x;
  const int wv = tid >> 6, l = tid & 63;
  const int l15 = l & 15, l4 = l >> 4;
  const int i0 = blockIdx.x * 64;
  const int b  = blockIdx.y;
  const int cbase = blockIdx.z * 64;
  const int rowbase = i0 + wv * 16;        // wave's 16 query rows

  const short* Qb = Q  + (size_t)b * NT * 64;
  const short* Kb = K  + (size_t)b * NT * 64;
  const short* Vb = Vt + (size_t)b * CF * NT;

  // Q fragments (B-operand: col=l15 -> query rowbase+l15, k=l4*8..)
  bf16x8 qf[2];
#pragma unroll
  for (int kk = 0; kk < 2; ++kk)
    qf[kk] = *(const bf16x8*)&Qb[(size_t)(rowbase + l15) * 64 + kk * 32 + l4 * 8];

  // permuted K row offset for A-operand (row a = l15 -> key kappa)
  const int kperm = 8 * (l15 >> 2) + (l15 & 3);

  bf16x8 kf[4][2];
#pragma unroll
  for (int nj = 0; nj < 4; ++nj) {
    const int knj = 32 * (nj >> 1) + 4 * (nj & 1);
#pragma unroll
    for (int kk = 0; kk < 2; ++kk)
      kf[nj][kk] = *(const bf16x8*)&Kb[(size_t)(knj + kperm) * 64 + kk * 32 + l4 * 8];
  }

  f32x4 acc[4] = {};          // O[i=4*l4+r][c=l15+16*nv], nv=0..3
  float mrow = -3.0e38f, lrow = 0.f;

  for (int jb = 0; jb < 64; ++jb) {
    const int j0 = jb * 64;

    // V loads first: PV needs them ~300cy later (QK + softmax window)
    bf16x8 vb[4][2];
#pragma unroll
    for (int nv = 0; nv < 4; ++nv)
#pragma unroll
      for (int kk = 0; kk < 2; ++kk)
        vb[nv][kk] = *(const bf16x8*)&Vb[(size_t)(cbase + 16 * nv + l15) * NT + j0 + 32 * kk + 8 * l4];

    // S^T = K_perm @ Q^T : s[nj] col=l15=query, row=4*l4+r -> key kappa
    f32x4 s[4];
#pragma unroll
    for (int nj = 0; nj < 4; ++nj) { f32x4 z = {0.f, 0.f, 0.f, 0.f}; s[nj] = z; }
#pragma unroll
    for (int kk = 0; kk < 2; ++kk)
#pragma unroll
      for (int nj = 0; nj < 4; ++nj)
        s[nj] = __builtin_amdgcn_mfma_f32_16x16x32_bf16(kf[nj][kk], qf[kk], s[nj], 0, 0, 0);

    // K prefetch for next tile (kf regs free once QK has issued)
    if (jb < 63) {
#pragma unroll
      for (int nj = 0; nj < 4; ++nj) {
        const int knj = 32 * (nj >> 1) + 4 * (nj & 1);
#pragma unroll
        for (int kk = 0; kk < 2; ++kk)
          kf[nj][kk] = *(const bf16x8*)&Kb[(size_t)(j0 + 64 + knj + kperm) * 64 + kk * 32 + l4 * 8];
      }
    }

    // --- online softmax (log2 domain), lane-local row = query l15 ---
    float mx = s[0][0];
#pragma unroll
    for (int nj = 0; nj < 4; ++nj)
#pragma unroll
      for (int r = 0; r < 4; ++r) mx = fmaxf(mx, s[nj][r]);
    mx = fmaxf(mx, __shfl_xor(mx, 16, 64));
    mx = fmaxf(mx, __shfl_xor(mx, 32, 64));

    // defer-max: skip O-rescale while max grows < 8 (ln) = 11.5416 (log2)
    if (!__all(mx <= mrow + 11.5416f)) {
      float mnew = fmaxf(mrow, mx);
      float sc = exp2f(mrow - mnew);
      mrow = mnew;
      lrow *= sc;
      float s0 = __shfl(sc, 4 * l4 + 0, 64);
      float s1 = __shfl(sc, 4 * l4 + 1, 64);
      float s2 = __shfl(sc, 4 * l4 + 2, 64);
      float s3 = __shfl(sc, 4 * l4 + 3, 64);
#pragma unroll
      for (int nv = 0; nv < 4; ++nv) {
        acc[nv][0] *= s0; acc[nv][1] *= s1; acc[nv][2] *= s2; acc[nv][3] *= s3;
      }
    }

    float rs = 0.f;
#pragma unroll
    for (int nj = 0; nj < 4; ++nj)
#pragma unroll
      for (int r = 0; r < 4; ++r) {
        float p = exp2f(s[nj][r] - mrow);
        s[nj][r] = p;
        rs += p;
      }
    rs += __shfl_xor(rs, 16, 64);
    rs += __shfl_xor(rs, 32, 64);
    lrow += rs;

    // pack P -> bf16 PV A-fragments entirely in-register
    unsigned pk[4][2];
#pragma unroll
    for (int nj = 0; nj < 4; ++nj)
#pragma unroll
      for (int h = 0; h < 2; ++h)
        asm("v_cvt_pk_bf16_f32 %0, %1, %2"
            : "=v"(pk[nj][h]) : "v"(s[nj][2 * h]), "v"(s[nj][2 * h + 1]));

    __builtin_amdgcn_s_setprio(1);
#pragma unroll
    for (int kk = 0; kk < 2; ++kk) {
      union { unsigned u[4]; bf16x8 v; } pa;
      pa.u[0] = pk[2 * kk][0]; pa.u[1] = pk[2 * kk][1];
      pa.u[2] = pk[2 * kk + 1][0]; pa.u[3] = pk[2 * kk + 1][1];
#pragma unroll
      for (int nv = 0; nv < 4; ++nv)
        acc[nv] = __builtin_amdgcn_mfma_f32_16x16x32_bf16(pa.v, vb[nv][kk], acc[nv], 0, 0, 0);
    }
    __builtin_amdgcn_s_setprio(0);
  }

  // --- epilogue: normalize, per-wave LDS transpose, fused residual ---
  float li[4];
#pragma unroll
  for (int r = 0; r < 4; ++r)
    li[r] = 1.0f / __shfl(lrow, 4 * l4 + r, 64);

#pragma unroll
  for (int nv = 0; nv < 4; ++nv)
#pragma unroll
    for (int r = 0; r < 4; ++r)
      Obuf[wv][4 * l4 + r][16 * nv + l15] = acc[nv][r] * li[r];
  // same-wave LDS write->read: compiler-inserted lgkmcnt, no barrier needed

  const float g = gamma_p[0];
  const float* srcb = src + (size_t)b * CF * NT;
  float* outb = out + (size_t)b * CF * NT;

#pragma unroll 4
  for (int t = 0; t < 16; ++t) {
    int c = cbase + l4 + 4 * t;
    size_t off = (size_t)c * NT + rowbase + l15;
    float v = Obuf[wv][l15][l4 + 4 * t];
    outb[off] = g * v + srcb[off];
  }
}

// ---------------------------------------------------------------------------
extern "C" void kernel_launch(void* const* d_in, const int* in_sizes, int n_in,
                              void* d_out, int out_size, void* d_ws, size_t ws_size,
                              hipStream_t stream) {
  const float* src    = (const float*)d_in[0];
  const float* ref    = (const float*)d_in[1];
  const float* w_src  = (const float*)d_in[2];
  const float* b_src  = (const float*)d_in[3];
  const float* w_ref  = (const float*)d_in[4];
  const float* b_ref  = (const float*)d_in[5];
  const float* w_gate = (const float*)d_in[6];
  const float* b_gate = (const float*)d_in[7];
  const float* gamma  = (const float*)d_in[8];
  float* out = (float*)d_out;

  const size_t qk_elems = (size_t)4 * NT * 64;
  const size_t v_elems  = (size_t)4 * CF * NT;
  if (ws_size < (qk_elems * 2 + v_elems) * sizeof(short)) return;
  short* Qw = (short*)d_ws;
  short* Kw = Qw + qk_elems;
  short* Vw = Kw + qk_elems;

  dim3 blk(256);
  dim3 gp(NT / 64, 4);
  // fold energy scale (1/16) AND log2(e) into Q so scores are log2-domain
  proj_kernel<64,  false><<<gp, blk, 0, stream>>>(src, w_src,  b_src,  Qw, 0.0625f * 1.44269504f);
  proj_kernel<64,  false><<<gp, blk, 0, stream>>>(ref, w_ref,  b_ref,  Kw, 1.0f);
  proj_kernel<256, true ><<<gp, blk, 0, stream>>>(ref, w_gate, b_gate, Vw, 1.0f);

  dim3 gf(NT / 64, 4, 4);   // q-tiles x batch x col-split(64)
  flash_kernel<<<gf, blk, 0, stream>>>(Qw, Kw, Vw, src, gamma, out);
}

// Round 4
// 164.048 us; speedup vs baseline: 3.0168x; 3.0168x over previous
//
#include <hip/hip_runtime.h>
#include <hip/hip_bf16.h>

#define NT 4096      // H*W
#define CF 256       // feature channels
// CQK = 64

typedef __attribute__((ext_vector_type(8))) short bf16x8;
typedef __attribute__((ext_vector_type(4))) float f32x4;
typedef __attribute__((ext_vector_type(4))) short s16x4;

__device__ __forceinline__ short f2bf(float f) {
  union { float f; unsigned u; } v; v.f = f;
  unsigned r = v.u + 0x7FFFu + ((v.u >> 16) & 1u);   // RTNE
  return (short)(r >> 16);
}

// async global->LDS, 16B per lane; LDS dest = wave-uniform base + lane*16
__device__ __forceinline__ void glds16(const void* g, void* l) {
  __builtin_amdgcn_global_load_lds(
      (const __attribute__((address_space(1))) void*)g,
      (__attribute__((address_space(3))) void*)l, 16, 0, 0);
}

// ---------------------------------------------------------------------------
// Projection: Y[i,o] = (sum_c X[c,i] * W[o,c] + bias[o]) * scale, bf16 output.
// TRANS=false -> Y (B,NT,O) row-major;  TRANS=true -> Y (B,O,NT).
// ---------------------------------------------------------------------------
template<int O, bool TRANS>
__global__ __launch_bounds__(256, 2)
void proj_kernel(const float* __restrict__ X, const float* __restrict__ W,
                 const float* __restrict__ Bv, short* __restrict__ Y, float scale)
{
  __shared__ alignas(16) short Xlds[64 * 256];   // [i][c] bf16, XOR-swizzled
  const int tid = threadIdx.x;
  const int wv = tid >> 6, l = tid & 63;
  const int l15 = l & 15, l4 = l >> 4;
  const int i0 = blockIdx.x * 64;
  const int b  = blockIdx.y;
  const float* Xb = X + (size_t)b * CF * NT;

#pragma unroll
  for (int it = 0; it < 16; ++it) {
    int c0 = it * 16 + wv * 4;
    float x0 = Xb[(size_t)(c0 + 0) * NT + i0 + l];
    float x1 = Xb[(size_t)(c0 + 1) * NT + i0 + l];
    float x2 = Xb[(size_t)(c0 + 2) * NT + i0 + l];
    float x3 = Xb[(size_t)(c0 + 3) * NT + i0 + l];
    s16x4 pk; pk[0] = f2bf(x0); pk[1] = f2bf(x1); pk[2] = f2bf(x2); pk[3] = f2bf(x3);
    int phys = (l * 512 + c0 * 2) ^ ((l & 31) << 4);
    *(s16x4*)((char*)Xlds + phys) = pk;
  }
  __syncthreads();

  constexpr int NO = O / 64;
  f32x4 acc[4][NO] = {};

#pragma unroll
  for (int kk = 0; kk < 8; ++kk) {
    bf16x8 a[4];
#pragma unroll
    for (int mi = 0; mi < 4; ++mi) {
      int i = 16 * mi + l15;
      int phys = (i * 512 + kk * 64 + l4 * 16) ^ ((i & 31) << 4);
      a[mi] = *(const bf16x8*)((const char*)Xlds + phys);
    }
#pragma unroll
    for (int no = 0; no < NO; ++no) {
      int o = wv * (O / 4) + 16 * no + l15;
      const float* wp = W + (size_t)o * CF + kk * 32 + l4 * 8;
      bf16x8 wf;
#pragma unroll
      for (int t = 0; t < 8; ++t) wf[t] = f2bf(wp[t]);
#pragma unroll
      for (int mi = 0; mi < 4; ++mi)
        acc[mi][no] = __builtin_amdgcn_mfma_f32_16x16x32_bf16(a[mi], wf, acc[mi][no], 0, 0, 0);
    }
  }

#pragma unroll
  for (int no = 0; no < NO; ++no) {
    int o = wv * (O / 4) + 16 * no + l15;
    float bv = Bv[o];
#pragma unroll
    for (int mi = 0; mi < 4; ++mi) {
      if (TRANS) {
        s16x4 pk;
#pragma unroll
        for (int r = 0; r < 4; ++r) pk[r] = f2bf((acc[mi][no][r] + bv) * scale);
        *(s16x4*)&Y[((size_t)b * O + o) * NT + i0 + 16 * mi + l4 * 4] = pk;
      } else {
#pragma unroll
        for (int r = 0; r < 4; ++r) {
          int i = i0 + 16 * mi + l4 * 4 + r;
          Y[((size_t)b * NT + i) * O + o] = f2bf((acc[mi][no][r] + bv) * scale);
        }
      }
    }
  }
}

// ---------------------------------------------------------------------------
// Flash attention + residual, LDS-staged K/V (global_load_lds, double-buffer).
// Q (B,NT,64) bf16 pre-scaled by (1/16)*log2(e), K (B,NT,64), Vt (B,256,NT).
// wg = 4 waves = 128 q-rows x 64 cols; wave = 32 q-rows (2 groups of 16).
// KVBLK=64. One __syncthreads per tile (implicit vmcnt(0) drains stages).
// LDS tiles XOR-swizzled: granule ^= (row&3) | (((row>>3)&1)<<2)  (bits 4,6 of
// byte addr). Staged with linear LDS dest + inverse-swizzled global source.
// Swapped QK^T with key permutation kappa -> P stays in registers (cvt_pk).
// ---------------------------------------------------------------------------
__global__ __launch_bounds__(256, 2)
void flash_kernel(const short* __restrict__ Q, const short* __restrict__ K,
                  const short* __restrict__ Vt, const float* __restrict__ src,
                  const float* __restrict__ gamma_p, float* __restrict__ out)
{
  // arena: K tiles [0,16K) (2 x 8KB), V tiles [16K,32K) (2 x 8KB);
  // reused as per-wave epilogue transpose buffers after the loop.
  __shared__ alignas(16) char arena[32768];

  const int tid = threadIdx.x;
  const int wv = tid >> 6, l = tid & 63;
  const int l15 = l & 15, l4 = l >> 4;

  // XCD-aware decode: blockIdx.x % 8 selects XCD (default round-robin);
  // give each batch a fixed XCD pair so K+V (2.5MB) stays in that L2.
  const int id = blockIdx.x;
  const int x8 = id & 7;
  const int b  = x8 >> 1;
  const int widx = ((id >> 3) << 1) | (x8 & 1);   // 0..127 within batch
  const int qt = widx >> 2;                        // 0..31
  const int z  = widx & 3;                         // 0..3
  const int i0 = qt * 128;
  const int cbase = z * 64;
  const int rowbase = i0 + wv * 32;                // wave's 32 query rows

  const short* Qb = Q + (size_t)b * NT * 64;
  const char*  Kb = (const char*)(K  + (size_t)b * NT * 64);
  const char*  Vb = (const char*)(Vt + (size_t)b * CF * NT);

  // Q fragments: 2 groups of 16 rows (B-operand: col=l15, k=l4*8..)
  bf16x8 qf[2][2];
#pragma unroll
  for (int g = 0; g < 2; ++g)
#pragma unroll
    for (int kk = 0; kk < 2; ++kk)
      qf[g][kk] = *(const bf16x8*)&Qb[(size_t)(rowbase + 16 * g + l15) * 64 + kk * 32 + l4 * 8];

  // ---- staging source addresses (chunk = (wv*2+i)*64 + lane) ----
  const char* sK[2]; const char* sV[2];
#pragma unroll
  for (int i = 0; i < 2; ++i) {
    int c = (wv * 2 + i) * 64 + l;
    int r = c >> 3, gch = c & 7;
    int swz = (r & 3) | (((r >> 3) & 1) << 2);
    sK[i] = Kb + r * 128 + ((gch ^ swz) << 4);
    sV[i] = Vb + (size_t)(cbase + r) * (NT * 2) + ((gch ^ swz) << 4);
  }

  // ---- reader per-lane byte offsets (loop-invariant) ----
  const int kperm = 8 * (l15 >> 2) + (l15 & 3);
  const int swzk = (l15 & 3) | (((l15 >> 2) & 1) << 2);
  const int swzv = (l15 & 3) | (((l15 >> 3) & 1) << 2);
  int baseK[2], baseV[2];
#pragma unroll
  for (int kk = 0; kk < 2; ++kk) {
    baseK[kk] = kperm * 128 + (((kk * 4 + l4) ^ swzk) << 4);
    baseV[kk] = l15 * 128 + (((kk * 4 + l4) ^ swzv) << 4);
  }

  // ---- prologue: stage tile 0 into buffer 0 ----
#pragma unroll
  for (int i = 0; i < 2; ++i) {
    glds16(sK[i], arena + (wv * 2 + i) * 1024);
    glds16(sV[i], arena + 16384 + (wv * 2 + i) * 1024);
    sK[i] += 8192; sV[i] += 128;
  }
  __syncthreads();

  f32x4 acc[2][4] = {};
  float mrow[2] = { -3.0e38f, -3.0e38f };
  float lrow[2] = { 0.f, 0.f };

  for (int jb = 0; jb < 64; ++jb) {
    const int cur = jb & 1;
    const char* Kc = arena + cur * 8192;
    const char* Vc = arena + 16384 + cur * 8192;

    // stage next tile into alternate buffers (async; lands before end barrier)
    if (jb < 63) {
      char* Kn = arena + (cur ^ 1) * 8192;
      char* Vn = arena + 16384 + (cur ^ 1) * 8192;
#pragma unroll
      for (int i = 0; i < 2; ++i) {
        glds16(sK[i], Kn + (wv * 2 + i) * 1024);
        glds16(sV[i], Vn + (wv * 2 + i) * 1024);
        sK[i] += 8192; sV[i] += 128;
      }
    }

    // K fragments (A-operand, permuted rows, swizzle-corrected)
    bf16x8 kf[4][2];
#pragma unroll
    for (int nj = 0; nj < 4; ++nj)
#pragma unroll
      for (int kk = 0; kk < 2; ++kk)
        kf[nj][kk] = *(const bf16x8*)(Kc + baseK[kk] + (nj >> 1) * 4096 + (nj & 1) * 512);

    // S^T = K_perm @ Q^T for both q-groups (kf shared)
    f32x4 s[2][4];
#pragma unroll
    for (int g = 0; g < 2; ++g)
#pragma unroll
      for (int nj = 0; nj < 4; ++nj) { f32x4 zz = {0.f,0.f,0.f,0.f}; s[g][nj] = zz; }
    __builtin_amdgcn_s_setprio(1);
#pragma unroll
    for (int kk = 0; kk < 2; ++kk)
#pragma unroll
      for (int nj = 0; nj < 4; ++nj)
#pragma unroll
        for (int g = 0; g < 2; ++g)
          s[g][nj] = __builtin_amdgcn_mfma_f32_16x16x32_bf16(kf[nj][kk], qf[g][kk], s[g][nj], 0, 0, 0);
    __builtin_amdgcn_s_setprio(0);

    // V fragments (B-operand, shared by both q-groups)
    bf16x8 vb[4][2];
#pragma unroll
    for (int nv = 0; nv < 4; ++nv)
#pragma unroll
      for (int kk = 0; kk < 2; ++kk)
        vb[nv][kk] = *(const bf16x8*)(Vc + baseV[kk] + nv * 2048);

    // online softmax (log2 domain) per q-group; P packed in-register
    bf16x8 pa[2][2];
#pragma unroll
    for (int g = 0; g < 2; ++g) {
      float mx = s[g][0][0];
#pragma unroll
      for (int nj = 0; nj < 4; ++nj)
#pragma unroll
        for (int r = 0; r < 4; ++r) mx = fmaxf(mx, s[g][nj][r]);
      mx = fmaxf(mx, __shfl_xor(mx, 16, 64));
      mx = fmaxf(mx, __shfl_xor(mx, 32, 64));

      if (!__all(mx <= mrow[g] + 11.5416f)) {   // defer-max THR=8 (ln) in log2
        float mnew = fmaxf(mrow[g], mx);
        float scn = exp2f(mrow[g] - mnew);
        mrow[g] = mnew;
        lrow[g] *= scn;
        float s0 = __shfl(scn, 4 * l4 + 0, 64);
        float s1 = __shfl(scn, 4 * l4 + 1, 64);
        float s2 = __shfl(scn, 4 * l4 + 2, 64);
        float s3 = __shfl(scn, 4 * l4 + 3, 64);
#pragma unroll
        for (int nv = 0; nv < 4; ++nv) {
          acc[g][nv][0] *= s0; acc[g][nv][1] *= s1;
          acc[g][nv][2] *= s2; acc[g][nv][3] *= s3;
        }
      }

      float rs = 0.f;
#pragma unroll
      for (int nj = 0; nj < 4; ++nj)
#pragma unroll
        for (int r = 0; r < 4; ++r) {
          float p = exp2f(s[g][nj][r] - mrow[g]);
          s[g][nj][r] = p;
          rs += p;
        }
      rs += __shfl_xor(rs, 16, 64);
      rs += __shfl_xor(rs, 32, 64);
      lrow[g] += rs;

      unsigned pk[4][2];
#pragma unroll
      for (int nj = 0; nj < 4; ++nj)
#pragma unroll
        for (int h = 0; h < 2; ++h)
          asm("v_cvt_pk_bf16_f32 %0, %1, %2"
              : "=v"(pk[nj][h]) : "v"(s[g][nj][2 * h]), "v"(s[g][nj][2 * h + 1]));
#pragma unroll
      for (int kk = 0; kk < 2; ++kk) {
        union { unsigned u[4]; bf16x8 v; } u;
        u.u[0] = pk[2 * kk][0];     u.u[1] = pk[2 * kk][1];
        u.u[2] = pk[2 * kk + 1][0]; u.u[3] = pk[2 * kk + 1][1];
        pa[g][kk] = u.v;
      }
    }

    // O += P @ V
    __builtin_amdgcn_s_setprio(1);
#pragma unroll
    for (int kk = 0; kk < 2; ++kk)
#pragma unroll
      for (int g = 0; g < 2; ++g)
#pragma unroll
        for (int nv = 0; nv < 4; ++nv)
          acc[g][nv] = __builtin_amdgcn_mfma_f32_16x16x32_bf16(pa[g][kk], vb[nv][kk], acc[g][nv], 0, 0, 0);
    __builtin_amdgcn_s_setprio(0);

    __syncthreads();   // implicit vmcnt(0): next-tile stage landed; reads done
  }

  // ---- epilogue: normalize, per-wave LDS transpose, fused residual ----
  float* Obuf = (float*)(void*)arena + wv * (16 * 68);
  const float gm = gamma_p[0];
  const float* srcb = src + (size_t)b * CF * NT;
  float* outb = out + (size_t)b * CF * NT;

#pragma unroll
  for (int g = 0; g < 2; ++g) {
    float li[4];
#pragma unroll
    for (int r = 0; r < 4; ++r)
      li[r] = 1.0f / __shfl(lrow[g], 4 * l4 + r, 64);
#pragma unroll
    for (int nv = 0; nv < 4; ++nv)
#pragma unroll
      for (int r = 0; r < 4; ++r)
        Obuf[(4 * l4 + r) * 68 + 16 * nv + l15] = acc[g][nv][r] * li[r];
#pragma unroll 4
    for (int t = 0; t < 16; ++t) {
      int c = cbase + l4 + 4 * t;
      size_t off = (size_t)c * NT + rowbase + 16 * g + l15;
      float v = Obuf[l15 * 68 + l4 + 4 * t];
      outb[off] = gm * v + srcb[off];
    }
  }
}

// ---------------------------------------------------------------------------
extern "C" void kernel_launch(void* const* d_in, const int* in_sizes, int n_in,
                              void* d_out, int out_size, void* d_ws, size_t ws_size,
                              hipStream_t stream) {
  const float* src    = (const float*)d_in[0];
  const float* ref    = (const float*)d_in[1];
  const float* w_src  = (const float*)d_in[2];
  const float* b_src  = (const float*)d_in[3];
  const float* w_ref  = (const float*)d_in[4];
  const float* b_ref  = (const float*)d_in[5];
  const float* w_gate = (const float*)d_in[6];
  const float* b_gate = (const float*)d_in[7];
  const float* gamma  = (const float*)d_in[8];
  float* out = (float*)d_out;

  const size_t qk_elems = (size_t)4 * NT * 64;
  const size_t v_elems  = (size_t)4 * CF * NT;
  if (ws_size < (qk_elems * 2 + v_elems) * sizeof(short)) return;
  short* Qw = (short*)d_ws;
  short* Kw = Qw + qk_elems;
  short* Vw = Kw + qk_elems;

  dim3 blk(256);
  dim3 gp(NT / 64, 4);
  // fold energy scale (1/16) AND log2(e) into Q so scores are log2-domain
  proj_kernel<64,  false><<<gp, blk, 0, stream>>>(src, w_src,  b_src,  Qw, 0.0625f * 1.44269504f);
  proj_kernel<64,  false><<<gp, blk, 0, stream>>>(ref, w_ref,  b_ref,  Kw, 1.0f);
  proj_kernel<256, true ><<<gp, blk, 0, stream>>>(ref, w_gate, b_gate, Vw, 1.0f);

  flash_kernel<<<dim3(512), blk, 0, stream>>>(Qw, Kw, Vw, src, gamma, out);
}